// Round 1
// baseline (1130.305 us; speedup 1.0000x reference)
//
#include <hip/hip_runtime.h>
#include <math.h>

#define P_DIM 1024
#define R_DIM 128
#define B_DIM 8
#define T_DIM 4096
#define NROWS (B_DIM*T_DIM)   // 32768

// ============================================================
// Stage 1: r = t@V_r ; u = (F*t)@V_b * scale ; a = clip(sigmoid(r@W + b))
// Outputs:
//   au_ws[row][256]: per scan-lane l, float4 {a[2l],a[2l+1],u[2l],u[2l+1]}
//   usq_ws[row]    : sum_k u[row][k]^2   (the scan's "C" term, off-loop)
// ============================================================
__global__ __launch_bounds__(256, 2) void stage1_kernel(
    const float* __restrict__ tin, const float* __restrict__ Fin,
    const float* __restrict__ Vr, const float* __restrict__ Vb,
    const float* __restrict__ Wl, const float* __restrict__ bl,
    float* __restrict__ au_ws, float* __restrict__ usq_ws)
{
    __shared__ float tA[32][36];
    __shared__ float tF[32][36];
    __shared__ float Bs[2][32][128];
    __shared__ float rS[32][132];

    const int tid  = threadIdx.x;
    const int c    = tid & 31;
    const int ry   = tid >> 5;
    const int row0 = blockIdx.x * 32;

    float accR[4][4] = {};
    float accU[4][4] = {};

    const int lr = tid >> 3;
    const int lk = (tid & 7) << 2;

    for (int k0 = 0; k0 < P_DIM; k0 += 32) {
        __syncthreads();
        float4 tv = *(const float4*)(tin + (long)(row0 + lr) * P_DIM + k0 + lk);
        float4 fv = *(const float4*)(Fin + (long)(row0 + lr) * P_DIM + k0 + lk);
        fv.x *= tv.x; fv.y *= tv.y; fv.z *= tv.z; fv.w *= tv.w;
        *(float4*)&tA[lr][lk] = tv;
        *(float4*)&tF[lr][lk] = fv;
#pragma unroll
        for (int i = 0; i < 4; i++) {
            int idx = tid + i * 256;
            ((float4*)&Bs[0][0][0])[idx] = ((const float4*)(Vr + (long)k0 * R_DIM))[idx];
            ((float4*)&Bs[1][0][0])[idx] = ((const float4*)(Vb + (long)k0 * R_DIM))[idx];
        }
        __syncthreads();
#pragma unroll
        for (int kk = 0; kk < 32; kk++) {
            float4 vr = *(const float4*)&Bs[0][kk][c * 4];
            float4 vb = *(const float4*)&Bs[1][kk][c * 4];
#pragma unroll
            for (int i = 0; i < 4; i++) {
                float ta = tA[ry * 4 + i][kk];
                float tf = tF[ry * 4 + i][kk];
                accR[i][0] = fmaf(ta, vr.x, accR[i][0]);
                accR[i][1] = fmaf(ta, vr.y, accR[i][1]);
                accR[i][2] = fmaf(ta, vr.z, accR[i][2]);
                accR[i][3] = fmaf(ta, vr.w, accR[i][3]);
                accU[i][0] = fmaf(tf, vb.x, accU[i][0]);
                accU[i][1] = fmaf(tf, vb.y, accU[i][1]);
                accU[i][2] = fmaf(tf, vb.z, accU[i][2]);
                accU[i][3] = fmaf(tf, vb.w, accU[i][3]);
            }
        }
    }

#pragma unroll
    for (int i = 0; i < 4; i++) {
        *(float4*)&rS[ry * 4 + i][c * 4] =
            make_float4(accR[i][0], accR[i][1], accR[i][2], accR[i][3]);
    }

    float4 bl4 = *(const float4*)(bl + c * 4);
    float z[4][4];
#pragma unroll
    for (int i = 0; i < 4; i++) { z[i][0] = bl4.x; z[i][1] = bl4.y; z[i][2] = bl4.z; z[i][3] = bl4.w; }

    for (int kc = 0; kc < R_DIM; kc += 32) {
        __syncthreads();
#pragma unroll
        for (int i2 = 0; i2 < 4; i2++) {
            int idx = tid + i2 * 256;
            ((float4*)&Bs[0][0][0])[idx] = ((const float4*)(Wl + (long)kc * R_DIM))[idx];
        }
        __syncthreads();
#pragma unroll
        for (int kk = 0; kk < 32; kk++) {
            float4 w = *(const float4*)&Bs[0][kk][c * 4];
#pragma unroll
            for (int i = 0; i < 4; i++) {
                float rv = rS[ry * 4 + i][kc + kk];
                z[i][0] = fmaf(rv, w.x, z[i][0]);
                z[i][1] = fmaf(rv, w.y, z[i][1]);
                z[i][2] = fmaf(rv, w.z, z[i][2]);
                z[i][3] = fmaf(rv, w.w, z[i][3]);
            }
        }
    }

    const float uscale = 0.08838834764831845f;  // 1/sqrt(128)
#pragma unroll
    for (int i = 0; i < 4; i++) {
        int row = row0 + ry * 4 + i;
        float4 av;
        av.x = fminf(fmaxf(1.f / (1.f + expf(-z[i][0])), 0.01f), 0.995f);
        av.y = fminf(fmaxf(1.f / (1.f + expf(-z[i][1])), 0.01f), 0.995f);
        av.z = fminf(fmaxf(1.f / (1.f + expf(-z[i][2])), 0.01f), 0.995f);
        av.w = fminf(fmaxf(1.f / (1.f + expf(-z[i][3])), 0.01f), 0.995f);
        float4 uv = make_float4(accU[i][0] * uscale, accU[i][1] * uscale,
                                accU[i][2] * uscale, accU[i][3] * uscale);
        // interleaved layout: scan lane 2c gets {av.x,av.y,uv.x,uv.y},
        // lane 2c+1 gets {av.z,av.w,uv.z,uv.w}
        float* dst = au_ws + ((long)row << 8) + c * 8;
        *(float4*)dst       = make_float4(av.x, av.y, uv.x, uv.y);
        *(float4*)(dst + 4) = make_float4(av.z, av.w, uv.z, uv.w);
        // C = sum(u^2) over the row: reduce across the 32 lanes sharing ry
        float us = fmaf(uv.x, uv.x, fmaf(uv.y, uv.y, fmaf(uv.z, uv.z, uv.w * uv.w)));
        us += __shfl_xor(us, 1);
        us += __shfl_xor(us, 2);
        us += __shfl_xor(us, 4);
        us += __shfl_xor(us, 8);
        us += __shfl_xor(us, 16);
        if (c == 0) usq_ws[row] = us;
    }
}

// ============================================================
// Stage 2: sequential normalized scan, software-pipelined.
//   v_i = a_i*s_{i-1} + u_i = inv_{i-1}*p_i + u_i,  p_i = a_i*v_{i-1}
//   sum(v_i^2) = inv_{i-1}^2*A_i + 2*inv_{i-1}*B_i + C_i
//     A_i = sum(p_i^2), B_i = sum(p_i*u_i)  -> launched one step EARLY
//     C_i = sum(u_i^2)                      -> precomputed in stage 1
// The DPP reduction latency overlaps the previous step's scalar chain.
// s_{i-1} is stored IN PLACE over au row i-1 (fully consumed by then).
// ============================================================
template <int CTRL, int ROW_MASK>
__device__ __forceinline__ float dpp_add(float x) {
    int xi = __float_as_int(x);
    int yi = __builtin_amdgcn_update_dpp(0, xi, CTRL, ROW_MASK, 0xf, false);
    return x + __int_as_float(yi);
}

__device__ __forceinline__ float wave64_sum(float x) {
    x = dpp_add<0xB1,  0xf>(x);  // xor 1
    x = dpp_add<0x4E,  0xf>(x);  // xor 2
    x = dpp_add<0x141, 0xf>(x);  // xor 4 (row_half_mirror)
    x = dpp_add<0x140, 0xf>(x);  // xor 8 (row_mirror)
    x = dpp_add<0x142, 0xa>(x);  // row_bcast:15 -> rows 1,3
    x = dpp_add<0x143, 0xc>(x);  // row_bcast:31 -> rows 2,3; lane63 = total
    return __int_as_float(__builtin_amdgcn_readlane(__float_as_int(x), 63));
}

#define PF 8   // 8-deep rotating prefetch: 8 steps * ~90cyc covers L2/L3 latency

__global__ __launch_bounds__(64) void scan_kernel(
    float* __restrict__ au,            // in: {a,u} rows; out: s rows (in-place)
    const float* __restrict__ usq,     // per-row C = sum(u^2)
    float* __restrict__ cache_out)
{
    const int b = blockIdx.x;
    const int lane = threadIdx.x;
    const long rowbase = (long)b * T_DIM;
    const float* usq_b = usq + rowbase;

    float4 buf[PF];
    float  cq[PF];
#pragma unroll
    for (int j = 0; j < PF; j++) {
        buf[j] = *(const float4*)(au + ((rowbase + j) << 8) + lane * 4);
        cq[j]  = usq_b[j];
    }

    float2 v   = make_float2(0.f, 0.f);  // v_{i-1}, unnormalized
    float invp = 0.f;                    // inv_{i-2}; dead at i=0 (A=B=C=0)
    float Ap = 0.f, Bp = 0.f, Cp = 0.f;  // step i-1 reduction results

    for (int i0 = 0; i0 < T_DIM; i0 += PF) {
#pragma unroll
        for (int j = 0; j < PF; j++) {
            const int i = i0 + j;
            float4 x = buf[j];           // {a0,a1,u0,u1}
            float  C = cq[j];
            int ip = i + PF; if (ip > T_DIM - 1) ip = T_DIM - 1;  // branchless tail
            buf[j] = *(const float4*)(au + ((rowbase + ip) << 8) + lane * 4);
            cq[j]  = usq_b[ip];

            // p_i and this step's reductions (do NOT need inv_{i-1})
            float px = x.x * v.x;
            float py = x.y * v.y;
            float pa = fmaf(px, px, py * py);
            float pb = fmaf(px, x.z, py * x.w);
            float A = wave64_sum(pa);
            float B = wave64_sum(pb);

            // inv_{i-1} from the PREVIOUS step's reductions (already in flight)
            float tot = fmaf(invp * invp, Ap, fmaf(invp + invp, Bp, Cp));
            tot = fmaxf(tot, 0.f);                       // guard fp cancellation
            float inv = rsqrtf(fmaf(tot, 0.0078125f, 1e-6f));  // /128 + eps

            // store s_{i-1} = inv_{i-1} * v_{i-1} over dead au row i-1
            int iw = (i > 0) ? i - 1 : 0;   // i=0 writes zeros, overwritten at i=1
            *(float2*)(au + ((rowbase + iw) << 8) + lane * 2) =
                make_float2(inv * v.x, inv * v.y);

            // v_i = inv_{i-1}*p_i + u_i
            v.x = fmaf(inv, px, x.z);
            v.y = fmaf(inv, py, x.w);

            invp = inv; Ap = A; Bp = B; Cp = C;
        }
    }

    // epilogue: finalize step T-1
    float tot = fmaf(invp * invp, Ap, fmaf(invp + invp, Bp, Cp));
    tot = fmaxf(tot, 0.f);
    float inv = rsqrtf(fmaf(tot, 0.0078125f, 1e-6f));
    float2 sfin = make_float2(inv * v.x, inv * v.y);
    *(float2*)(au + ((rowbase + (T_DIM - 1)) << 8) + lane * 2) = sfin;
    *(float2*)(cache_out + b * R_DIM + lane * 2) = sfin;
}

// ============================================================
// Stage 3: t_tilde = s @ V_o + t.   s rows live at stride 256 inside au_ws.
// ============================================================
__global__ __launch_bounds__(256, 2) void stage3_kernel(
    const float* __restrict__ s_ws, const float* __restrict__ Vo,
    const float* __restrict__ tin, float* __restrict__ out)
{
    __shared__ float sS[16][128];
    __shared__ float VoS[32][256];

    const int tid = threadIdx.x;
    const int cb = blockIdx.x & 3;
    const int rb = blockIdx.x >> 2;
    const int row0 = rb * 16;
    const int col0 = cb * 256;
    const int tx = tid & 63;
    const int ty = tid >> 6;

    float acc[4][4] = {};

#pragma unroll
    for (int i = 0; i < 2; i++) {
        int idx = tid + i * 256;     // 0..511 = 16 rows x 32 quads
        int r = idx >> 5;
        int q = idx & 31;
        *(float4*)&sS[r][q * 4] =
            *(const float4*)(s_ws + ((long)(row0 + r) << 8) + q * 4);
    }

    for (int k0 = 0; k0 < R_DIM; k0 += 32) {
        __syncthreads();
#pragma unroll
        for (int i = 0; i < 8; i++) {
            int idx = tid + i * 256;
            int r = idx >> 6;
            int cq = idx & 63;
            *(float4*)&VoS[r][cq * 4] =
                *(const float4*)(Vo + (long)(k0 + r) * P_DIM + col0 + cq * 4);
        }
        __syncthreads();
#pragma unroll
        for (int kk = 0; kk < 32; kk++) {
            float4 w = *(const float4*)&VoS[kk][tx * 4];
#pragma unroll
            for (int i = 0; i < 4; i++) {
                float sv = sS[ty * 4 + i][k0 + kk];
                acc[i][0] = fmaf(sv, w.x, acc[i][0]);
                acc[i][1] = fmaf(sv, w.y, acc[i][1]);
                acc[i][2] = fmaf(sv, w.z, acc[i][2]);
                acc[i][3] = fmaf(sv, w.w, acc[i][3]);
            }
        }
    }

#pragma unroll
    for (int i = 0; i < 4; i++) {
        int row = row0 + ty * 4 + i;
        float4 tv = *(const float4*)(tin + (long)row * P_DIM + col0 + tx * 4);
        float4 o = make_float4(acc[i][0] + tv.x, acc[i][1] + tv.y,
                               acc[i][2] + tv.z, acc[i][3] + tv.w);
        *(float4*)(out + (long)row * P_DIM + col0 + tx * 4) = o;
    }
}

extern "C" void kernel_launch(void* const* d_in, const int* in_sizes, int n_in,
                              void* d_out, int out_size, void* d_ws, size_t ws_size,
                              hipStream_t stream) {
    const float* t  = (const float*)d_in[0];
    const float* F  = (const float*)d_in[1];
    const float* Vr = (const float*)d_in[2];
    const float* Vb = (const float*)d_in[3];
    const float* Vo = (const float*)d_in[4];
    const float* Wl = (const float*)d_in[5];
    const float* bl = (const float*)d_in[6];
    float* out = (float*)d_out;

    float* au_ws  = (float*)d_ws;                     // 32 MB: {a,u} then s in-place
    float* usq_ws = au_ws + (long)NROWS * 256;        // 128 KB: per-row sum(u^2)

    hipLaunchKernelGGL(stage1_kernel, dim3(NROWS / 32), dim3(256), 0, stream,
                       t, F, Vr, Vb, Wl, bl, au_ws, usq_ws);
    hipLaunchKernelGGL(scan_kernel, dim3(B_DIM), dim3(64), 0, stream,
                       au_ws, usq_ws, out + (long)NROWS * P_DIM);
    hipLaunchKernelGGL(stage3_kernel, dim3((NROWS / 16) * 4), dim3(256), 0, stream,
                       au_ws, Vo, t, out);
}

// Round 3
// 1088.896 us; speedup vs baseline: 1.0380x; 1.0380x over previous
//
#include <hip/hip_runtime.h>
#include <math.h>

#define P_DIM 1024
#define R_DIM 128
#define B_DIM 8
#define T_DIM 4096
#define NROWS (B_DIM*T_DIM)   // 32768

// ============================================================
// Stage 1: r = t@V_r ; u = (F*t)@V_b * scale ; a = clip(sigmoid(r@W + b))
// Outputs:
//   au_ws[row][256]: per scan-lane l, float4 {a[2l],a[2l+1],u[2l],u[2l+1]}
//   usq_ws[row]    : sum_k u[row][k]^2   (the scan's "C" term, off-loop)
// ============================================================
__global__ __launch_bounds__(256, 2) void stage1_kernel(
    const float* __restrict__ tin, const float* __restrict__ Fin,
    const float* __restrict__ Vr, const float* __restrict__ Vb,
    const float* __restrict__ Wl, const float* __restrict__ bl,
    float* __restrict__ au_ws, float* __restrict__ usq_ws)
{
    __shared__ float tA[32][36];
    __shared__ float tF[32][36];
    __shared__ float Bs[2][32][128];
    __shared__ float rS[32][132];

    const int tid  = threadIdx.x;
    const int c    = tid & 31;
    const int ry   = tid >> 5;
    const int row0 = blockIdx.x * 32;

    float accR[4][4] = {};
    float accU[4][4] = {};

    const int lr = tid >> 3;
    const int lk = (tid & 7) << 2;

    for (int k0 = 0; k0 < P_DIM; k0 += 32) {
        __syncthreads();
        float4 tv = *(const float4*)(tin + (long)(row0 + lr) * P_DIM + k0 + lk);
        float4 fv = *(const float4*)(Fin + (long)(row0 + lr) * P_DIM + k0 + lk);
        fv.x *= tv.x; fv.y *= tv.y; fv.z *= tv.z; fv.w *= tv.w;
        *(float4*)&tA[lr][lk] = tv;
        *(float4*)&tF[lr][lk] = fv;
#pragma unroll
        for (int i = 0; i < 4; i++) {
            int idx = tid + i * 256;
            ((float4*)&Bs[0][0][0])[idx] = ((const float4*)(Vr + (long)k0 * R_DIM))[idx];
            ((float4*)&Bs[1][0][0])[idx] = ((const float4*)(Vb + (long)k0 * R_DIM))[idx];
        }
        __syncthreads();
#pragma unroll
        for (int kk = 0; kk < 32; kk++) {
            float4 vr = *(const float4*)&Bs[0][kk][c * 4];
            float4 vb = *(const float4*)&Bs[1][kk][c * 4];
#pragma unroll
            for (int i = 0; i < 4; i++) {
                float ta = tA[ry * 4 + i][kk];
                float tf = tF[ry * 4 + i][kk];
                accR[i][0] = fmaf(ta, vr.x, accR[i][0]);
                accR[i][1] = fmaf(ta, vr.y, accR[i][1]);
                accR[i][2] = fmaf(ta, vr.z, accR[i][2]);
                accR[i][3] = fmaf(ta, vr.w, accR[i][3]);
                accU[i][0] = fmaf(tf, vb.x, accU[i][0]);
                accU[i][1] = fmaf(tf, vb.y, accU[i][1]);
                accU[i][2] = fmaf(tf, vb.z, accU[i][2]);
                accU[i][3] = fmaf(tf, vb.w, accU[i][3]);
            }
        }
    }

#pragma unroll
    for (int i = 0; i < 4; i++) {
        *(float4*)&rS[ry * 4 + i][c * 4] =
            make_float4(accR[i][0], accR[i][1], accR[i][2], accR[i][3]);
    }

    float4 bl4 = *(const float4*)(bl + c * 4);
    float z[4][4];
#pragma unroll
    for (int i = 0; i < 4; i++) { z[i][0] = bl4.x; z[i][1] = bl4.y; z[i][2] = bl4.z; z[i][3] = bl4.w; }

    for (int kc = 0; kc < R_DIM; kc += 32) {
        __syncthreads();
#pragma unroll
        for (int i2 = 0; i2 < 4; i2++) {
            int idx = tid + i2 * 256;
            ((float4*)&Bs[0][0][0])[idx] = ((const float4*)(Wl + (long)kc * R_DIM))[idx];
        }
        __syncthreads();
#pragma unroll
        for (int kk = 0; kk < 32; kk++) {
            float4 w = *(const float4*)&Bs[0][kk][c * 4];
#pragma unroll
            for (int i = 0; i < 4; i++) {
                float rv = rS[ry * 4 + i][kc + kk];
                z[i][0] = fmaf(rv, w.x, z[i][0]);
                z[i][1] = fmaf(rv, w.y, z[i][1]);
                z[i][2] = fmaf(rv, w.z, z[i][2]);
                z[i][3] = fmaf(rv, w.w, z[i][3]);
            }
        }
    }

    const float uscale = 0.08838834764831845f;  // 1/sqrt(128)
#pragma unroll
    for (int i = 0; i < 4; i++) {
        int row = row0 + ry * 4 + i;
        float4 av;
        av.x = fminf(fmaxf(1.f / (1.f + expf(-z[i][0])), 0.01f), 0.995f);
        av.y = fminf(fmaxf(1.f / (1.f + expf(-z[i][1])), 0.01f), 0.995f);
        av.z = fminf(fmaxf(1.f / (1.f + expf(-z[i][2])), 0.01f), 0.995f);
        av.w = fminf(fmaxf(1.f / (1.f + expf(-z[i][3])), 0.01f), 0.995f);
        float4 uv = make_float4(accU[i][0] * uscale, accU[i][1] * uscale,
                                accU[i][2] * uscale, accU[i][3] * uscale);
        // interleaved layout: scan lane 2c gets {av.x,av.y,uv.x,uv.y},
        // lane 2c+1 gets {av.z,av.w,uv.z,uv.w}
        float* dst = au_ws + ((long)row << 8) + c * 8;
        *(float4*)dst       = make_float4(av.x, av.y, uv.x, uv.y);
        *(float4*)(dst + 4) = make_float4(av.z, av.w, uv.z, uv.w);
        // C = sum(u^2) over the row: reduce across the 32 lanes sharing ry
        float us = fmaf(uv.x, uv.x, fmaf(uv.y, uv.y, fmaf(uv.z, uv.z, uv.w * uv.w)));
        us += __shfl_xor(us, 1);
        us += __shfl_xor(us, 2);
        us += __shfl_xor(us, 4);
        us += __shfl_xor(us, 8);
        us += __shfl_xor(us, 16);
        if (c == 0) usq_ws[row] = us;
    }
}

// ============================================================
// Stage 2: sequential normalized scan, software-pipelined.
//   v_i = a_i*s_{i-1} + u_i = inv_{i-1}*p_i + u_i,  p_i = a_i*v_{i-1}
//   sum(v_i^2) = inv_{i-1}^2*A_i + 2*inv_{i-1}*B_i + C_i
//     A_i = sum(p_i^2), B_i = sum(p_i*u_i)  -> launched one step EARLY
//     C_i = sum(u_i^2)                      -> precomputed in stage 1
// Loads (au, usq) and stores (s_ws) go through DISTINCT __restrict__
// pointers so the 16-deep prefetch is never drained by store ordering.
// ============================================================
template <int CTRL, int ROW_MASK>
__device__ __forceinline__ float dpp_add(float x) {
    int xi = __float_as_int(x);
    int yi = __builtin_amdgcn_update_dpp(0, xi, CTRL, ROW_MASK, 0xf, false);
    return x + __int_as_float(yi);
}

__device__ __forceinline__ float wave64_sum(float x) {
    x = dpp_add<0xB1,  0xf>(x);  // xor 1
    x = dpp_add<0x4E,  0xf>(x);  // xor 2
    x = dpp_add<0x141, 0xf>(x);  // xor 4 (row_half_mirror)
    x = dpp_add<0x140, 0xf>(x);  // xor 8 (row_mirror)
    x = dpp_add<0x142, 0xa>(x);  // row_bcast:15 -> rows 1,3
    x = dpp_add<0x143, 0xc>(x);  // row_bcast:31 -> rows 2,3; lane63 = total
    return __int_as_float(__builtin_amdgcn_readlane(__float_as_int(x), 63));
}

#define PF 16   // 16-deep rotating prefetch: covers L3/HBM latency at ~60cy/step

__global__ __launch_bounds__(64) void scan_kernel(
    const float* __restrict__ au,      // in: {a,u} interleaved rows (stride 256)
    const float* __restrict__ usq,     // in: per-row C = sum(u^2)
    float* __restrict__ s_ws,          // out: s rows (stride 128)
    float* __restrict__ cache_out)
{
    const int b = blockIdx.x;
    const int lane = threadIdx.x;
    const long rowbase = (long)b * T_DIM;
    const float* usq_b = usq + rowbase;
    const float* au_b  = au + (rowbase << 8) + lane * 4;
    float*       s_b   = s_ws + (rowbase << 7) + lane * 2;

    float4 buf[PF];
    float  cq[PF];
#pragma unroll
    for (int j = 0; j < PF; j++) {
        buf[j] = *(const float4*)(au_b + ((long)j << 8));
        cq[j]  = usq_b[j];
    }

    float2 v   = make_float2(0.f, 0.f);  // v_{i-1}, unnormalized
    float invp = 0.f;                    // inv_{i-2}; dead at i=0 (A=B=C=0)
    float Ap = 0.f, Bp = 0.f, Cp = 0.f;  // step i-1 reduction results

    for (int i0 = 0; i0 < T_DIM; i0 += PF) {
#pragma unroll
        for (int j = 0; j < PF; j++) {
            const int i = i0 + j;
            float4 x = buf[j];           // {a0,a1,u0,u1}
            float  C = cq[j];
            int ip = i + PF; if (ip > T_DIM - 1) ip = T_DIM - 1;  // branchless tail
            buf[j] = *(const float4*)(au_b + ((long)ip << 8));
            cq[j]  = usq_b[ip];

            // p_i and this step's reductions (do NOT need inv_{i-1})
            float px = x.x * v.x;
            float py = x.y * v.y;
            float pa = fmaf(px, px, py * py);
            float pb = fmaf(px, x.z, py * x.w);
            float A = wave64_sum(pa);
            float B = wave64_sum(pb);

            // inv_{i-1} from the PREVIOUS step's reductions (already in flight)
            float tot = fmaf(invp * invp, Ap, fmaf(invp + invp, Bp, Cp));
            tot = fmaxf(tot, 0.f);                       // guard fp cancellation
            float inv = rsqrtf(fmaf(tot, 0.0078125f, 1e-6f));  // /128 + eps

            // store s_{i-1} = inv_{i-1} * v_{i-1}
            int iw = (i > 0) ? i - 1 : 0;   // i=0 writes zeros, overwritten at i=1
            *(float2*)(s_b + ((long)iw << 7)) =
                make_float2(inv * v.x, inv * v.y);

            // v_i = inv_{i-1}*p_i + u_i
            v.x = fmaf(inv, px, x.z);
            v.y = fmaf(inv, py, x.w);

            invp = inv; Ap = A; Bp = B; Cp = C;
        }
    }

    // epilogue: finalize step T-1
    float tot = fmaf(invp * invp, Ap, fmaf(invp + invp, Bp, Cp));
    tot = fmaxf(tot, 0.f);
    float inv = rsqrtf(fmaf(tot, 0.0078125f, 1e-6f));
    float2 sfin = make_float2(inv * v.x, inv * v.y);
    *(float2*)(s_b + ((long)(T_DIM - 1) << 7)) = sfin;
    *(float2*)(cache_out + b * R_DIM + lane * 2) = sfin;
}

// ============================================================
// Stage 3: t_tilde = s @ V_o + t.   s rows compact (stride 128).
// ============================================================
__global__ __launch_bounds__(256, 2) void stage3_kernel(
    const float* __restrict__ s_ws, const float* __restrict__ Vo,
    const float* __restrict__ tin, float* __restrict__ out)
{
    __shared__ float sS[16][128];
    __shared__ float VoS[32][256];

    const int tid = threadIdx.x;
    const int cb = blockIdx.x & 3;
    const int rb = blockIdx.x >> 2;
    const int row0 = rb * 16;
    const int col0 = cb * 256;
    const int tx = tid & 63;
    const int ty = tid >> 6;

    float acc[4][4] = {};

#pragma unroll
    for (int i = 0; i < 2; i++) {
        int idx = tid + i * 256;
        ((float4*)&sS[0][0])[idx] = *(const float4*)(s_ws + (long)row0 * R_DIM + idx * 4);
    }

    for (int k0 = 0; k0 < R_DIM; k0 += 32) {
        __syncthreads();
#pragma unroll
        for (int i = 0; i < 8; i++) {
            int idx = tid + i * 256;
            int r = idx >> 6;
            int cq = idx & 63;
            *(float4*)&VoS[r][cq * 4] =
                *(const float4*)(Vo + (long)(k0 + r) * P_DIM + col0 + cq * 4);
        }
        __syncthreads();
#pragma unroll
        for (int kk = 0; kk < 32; kk++) {
            float4 w = *(const float4*)&VoS[kk][tx * 4];
#pragma unroll
            for (int i = 0; i < 4; i++) {
                float sv = sS[ty * 4 + i][k0 + kk];
                acc[i][0] = fmaf(sv, w.x, acc[i][0]);
                acc[i][1] = fmaf(sv, w.y, acc[i][1]);
                acc[i][2] = fmaf(sv, w.z, acc[i][2]);
                acc[i][3] = fmaf(sv, w.w, acc[i][3]);
            }
        }
    }

#pragma unroll
    for (int i = 0; i < 4; i++) {
        int row = row0 + ty * 4 + i;
        float4 tv = *(const float4*)(tin + (long)row * P_DIM + col0 + tx * 4);
        float4 o = make_float4(acc[i][0] + tv.x, acc[i][1] + tv.y,
                               acc[i][2] + tv.z, acc[i][3] + tv.w);
        *(float4*)(out + (long)row * P_DIM + col0 + tx * 4) = o;
    }
}

extern "C" void kernel_launch(void* const* d_in, const int* in_sizes, int n_in,
                              void* d_out, int out_size, void* d_ws, size_t ws_size,
                              hipStream_t stream) {
    const float* t  = (const float*)d_in[0];
    const float* F  = (const float*)d_in[1];
    const float* Vr = (const float*)d_in[2];
    const float* Vb = (const float*)d_in[3];
    const float* Vo = (const float*)d_in[4];
    const float* Wl = (const float*)d_in[5];
    const float* bl = (const float*)d_in[6];
    float* out = (float*)d_out;

    float* au_ws  = (float*)d_ws;                     // 32 MB: {a,u} interleaved
    float* usq_ws = au_ws + (long)NROWS * 256;        // 128 KB: per-row sum(u^2)
    float* s_ws   = usq_ws + NROWS;                   // 16 MB: s rows

    hipLaunchKernelGGL(stage1_kernel, dim3(NROWS / 32), dim3(256), 0, stream,
                       t, F, Vr, Vb, Wl, bl, au_ws, usq_ws);
    hipLaunchKernelGGL(scan_kernel, dim3(B_DIM), dim3(64), 0, stream,
                       au_ws, usq_ws, s_ws, out + (long)NROWS * P_DIM);
    hipLaunchKernelGGL(stage3_kernel, dim3((NROWS / 16) * 4), dim3(256), 0, stream,
                       s_ws, Vo, t, out);
}